// Round 8
// baseline (428.461 us; speedup 1.0000x reference)
//
#include <hip/hip_runtime.h>

#define HD 1024
#define ID 4096
#define NR 8192

typedef float f32x4 __attribute__((ext_vector_type(4)));
typedef __bf16 bf16x8 __attribute__((ext_vector_type(8)));

__device__ inline ushort f2bf(float f) {
    union { float f; unsigned u; } v; v.f = f;
    unsigned u = v.u;
    unsigned r = (u + 0x7fffu + ((u >> 16) & 1u)) >> 16;  // RNE
    return (ushort)r;
}

__device__ inline float wave_sum(float v) {
#pragma unroll
    for (int o = 32; o > 0; o >>= 1) v += __shfl_xor(v, o, 64);
    return v;
}

template <int N> __device__ __forceinline__ void vmw() {
    static_assert(N >= 0 && N <= 12, "vmcnt");
    if constexpr (N == 0) asm volatile("s_waitcnt vmcnt(0)" ::: "memory");
    else if constexpr (N == 1) asm volatile("s_waitcnt vmcnt(1)" ::: "memory");
    else if constexpr (N == 2) asm volatile("s_waitcnt vmcnt(2)" ::: "memory");
    else if constexpr (N == 3) asm volatile("s_waitcnt vmcnt(3)" ::: "memory");
    else if constexpr (N == 4) asm volatile("s_waitcnt vmcnt(4)" ::: "memory");
    else if constexpr (N == 11) asm volatile("s_waitcnt vmcnt(11)" ::: "memory");
    else if constexpr (N == 12) asm volatile("s_waitcnt vmcnt(12)" ::: "memory");
}
__device__ __forceinline__ void barrier_() {
    __builtin_amdgcn_sched_barrier(0);
    __builtin_amdgcn_s_barrier();
    __builtin_amdgcn_sched_barrier(0);
}
__device__ __forceinline__ void lgk0_() {
    asm volatile("s_waitcnt lgkmcnt(0)" ::: "memory");
    __builtin_amdgcn_sched_barrier(0);
}

// YOSO activation: t = 1 - acos(s)/pi via A&S 4.4.45 (|err| <= 6.7e-5 rad), out t^9.
__device__ __forceinline__ float yoso_act(float v) {
    float s = fminf(fmaxf(v, -0.999999f), 0.999999f);
    float a = fabsf(s);
    float p = 0.49998557f + a * (-0.06751706f + a * (0.02363794f - a * 0.00596170f));
    float q = sqrtf(1.0f - a) * p;           // acos(|s|)/pi
    float tt = (s >= 0.0f) ? 1.0f - q : q;
    float t2 = tt * tt, t4 = t2 * t2, t8 = t4 * t4;
    return t8 * tt;
}

// ======== GEMM1 ablation kernel: persistent 4-tile 256x128, BK=64, 8 waves, 1 blk/CU ========
// ABL=0: full (R7 kernel, correct output). ABL=1: NO staging/vmcnt (schedule+LDS+MFMA floor;
// reads uninit LDS, garbage out — overwritten by the later ABL=0 pass). ABL=2: NO epilogue
// stores (asm sinks keep acc/MFMA live; measures loop+staging without the store path).
template <int ABL>
__global__ __launch_bounds__(512, 2) void gemm1p_abl(
    const ushort* __restrict__ Ap, const ushort* __restrict__ Bp,
    ushort* __restrict__ Cp, int N, int K) {
    __shared__ char lds[131072] __attribute__((aligned(16)));
    const int tid = threadIdx.x;
    const int w = tid >> 6, l = tid & 63;
    const int wm = w >> 2, wn = w & 3;
    const int bid = blockIdx.x;
    const int xcd = bid & 7, cu = bid >> 3;
    const int brow = (xcd * 4 + (cu >> 3)) * 256;
    const int bcol0 = (cu & 7) * 512;
    const int colsw = ((l & 7) ^ (l >> 3)) << 4;

    f32x4 acc[8][2] = {};
    bf16x8 areg[4][2];
    bf16x8 breg[2][2];

    auto sA = [&](int u, int mh) {
        const int kt = u & 15, db = u & 1;
#pragma unroll
        for (int i = 0; i < 2; ++i) {
            int s = (w * 2 + i) * 8 + (l >> 3);
            int r = ((s >> 6) << 7) + mh * 64 + (s & 63);
            const char* src = (const char*)Ap + (((size_t)(brow + r) * K + kt * 64) << 1) + colsw;
            __builtin_amdgcn_global_load_lds(
                (const __attribute__((address_space(1))) void*)src,
                (__attribute__((address_space(3))) void*)&lds[db * 32768 + mh * 16384 +
                                                              (w * 2 + i) * 1024],
                16, 0, 0);
        }
    };
    auto sB = [&](int u, int nh) {
        const int kt = u & 15, db = u & 1;
        const int bcol = bcol0 + ((u >> 4) << 7);
        int s = w * 8 + (l >> 3);
        int r = ((s >> 4) << 5) + nh * 16 + (s & 15);
        const char* src = (const char*)Bp + (((size_t)(bcol + r) * K + kt * 64) << 1) + colsw;
        __builtin_amdgcn_global_load_lds(
            (const __attribute__((address_space(1))) void*)src,
            (__attribute__((address_space(3))) void*)&lds[65536 + db * 16384 + nh * 8192 + w * 1024],
            16, 0, 0);
    };
    auto load_a = [&](int db, int mh) {
#pragma unroll
        for (int m = 0; m < 4; ++m)
#pragma unroll
            for (int ks = 0; ks < 2; ++ks) {
                int s = wm * 64 + m * 16 + (l & 15);
                areg[m][ks] = *(const bf16x8*)(lds + db * 32768 + mh * 16384 + s * 128 +
                                               ((ks * 64 + ((l >> 4) << 4)) ^ ((l & 7) << 4)));
            }
    };
    auto load_b = [&](int db, int nh) {
#pragma unroll
        for (int ks = 0; ks < 2; ++ks) {
            int s = wn * 16 + (l & 15);
            breg[nh][ks] = *(const bf16x8*)(lds + 65536 + db * 16384 + nh * 8192 + s * 128 +
                                            ((ks * 64 + ((l >> 4) << 4)) ^ ((l & 7) << 4)));
        }
    };
    auto mma = [&](int mh, int nh) {
#pragma unroll
        for (int m = 0; m < 4; ++m)
#pragma unroll
            for (int ks = 0; ks < 2; ++ks)
                acc[mh * 4 + m][nh] = __builtin_amdgcn_mfma_f32_16x16x32_bf16(
                    areg[m][ks], breg[nh][ks], acc[mh * 4 + m][nh], 0, 0, 0);
    };
    auto epilogue = [&](int j) {
        char* wsl = lds + 98304 + w * 4096;
        const int bcol = bcol0 + j * 128;
#pragma unroll
        for (int p = 0; p < 2; ++p) {
#pragma unroll
            for (int mm = 0; mm < 4; ++mm)
#pragma unroll
                for (int n = 0; n < 2; ++n)
#pragma unroll
                    for (int r = 0; r < 4; ++r) {
                        int row = mm * 16 + ((l >> 4) << 2) + r;
                        int colb = (n * 16 + (l & 15)) * 2;
                        *(ushort*)(wsl + row * 64 + (colb ^ (((row >> 2) & 3) << 4))) =
                            f2bf(yoso_act(acc[p * 4 + mm][n][r]));
                    }
            asm volatile("s_waitcnt lgkmcnt(0)" ::: "memory");
#pragma unroll
            for (int it = 0; it < 4; ++it) {
                int row = it * 16 + (l >> 2);
                int cb = (l & 3) * 16;
                uint4 d = *(const uint4*)(wsl + row * 64 + (cb ^ (((row >> 2) & 3) << 4)));
                int grow = brow + wm * 128 + p * 64 + row;
                size_t off = ((size_t)grow * N + (bcol + wn * 32)) * 2 + cb;
                *(uint4*)((char*)Cp + off) = d;
            }
        }
#pragma unroll
        for (int m = 0; m < 8; ++m)
#pragma unroll
            for (int n = 0; n < 2; ++n) acc[m][n] = (f32x4){0.f, 0.f, 0.f, 0.f};
    };

    if constexpr (ABL != 1) {
        sA(0, 0); sB(0, 0); sB(0, 1); sA(0, 1);
        vmw<3>();
    }
    barrier_();

    for (int j = 0; j < 4; ++j) {
        for (int kt = 0; kt < 16; ++kt) {
            const int u = j * 16 + kt;
            const int db = kt & 1;
            const bool more = (u + 1 < 64);
            const bool post = (kt == 0 && j > 0);
            // ph1
            load_a(db, 0); load_b(db, 0);
            if constexpr (ABL != 1) { if (more) sA(u + 1, 0); }
            barrier_(); lgk0_();
            __builtin_amdgcn_s_setprio(1); mma(0, 0); __builtin_amdgcn_s_setprio(0);
            __builtin_amdgcn_sched_barrier(0);
            if constexpr (ABL != 1) { if (post) vmw<12>(); else if (more) vmw<4>(); else vmw<2>(); }
            barrier_();
            // ph2
            load_b(db, 1);
            if constexpr (ABL != 1) { if (more) sB(u + 1, 0); }
            barrier_(); lgk0_();
            __builtin_amdgcn_s_setprio(1); mma(0, 1); __builtin_amdgcn_s_setprio(0);
            __builtin_amdgcn_sched_barrier(0);
            if constexpr (ABL != 1) { if (post) vmw<11>(); else if (more) vmw<3>(); else vmw<0>(); }
            barrier_();
            // ph3
            load_a(db, 1);
            if constexpr (ABL != 1) { if (more) sB(u + 1, 1); }
            barrier_(); lgk0_();
            __builtin_amdgcn_s_setprio(1); mma(1, 1); __builtin_amdgcn_s_setprio(0);
            barrier_();
            // ph4
            if constexpr (ABL != 1) { if (more) sA(u + 1, 1); }
            barrier_();
            __builtin_amdgcn_s_setprio(1); mma(1, 0); __builtin_amdgcn_s_setprio(0);
            __builtin_amdgcn_sched_barrier(0);
            if constexpr (ABL != 1) { if (more) vmw<3>(); }
            barrier_();
        }
        if constexpr (ABL == 2) {
            // sink accumulators (rule 17: keep MFMA live without the store path)
#pragma unroll
            for (int m = 0; m < 8; ++m)
#pragma unroll
                for (int n = 0; n < 2; ++n) {
                    asm volatile("" ::"v"(acc[m][n][0]), "v"(acc[m][n][1]),
                                 "v"(acc[m][n][2]), "v"(acc[m][n][3]));
                    acc[m][n] = (f32x4){0.f, 0.f, 0.f, 0.f};
                }
        } else {
            epilogue(j);
        }
    }
}

// ================= gemm8p: proven 8-phase 256x128 (ACT=0, f32 out) ==========
template <int NW, int ACT>
__global__ __launch_bounds__(512, 2) void gemm8p_kernel(
    const ushort* __restrict__ Ap, const ushort* __restrict__ Bp,
    void* __restrict__ Cv, int N, int K, int nt) {
    __shared__ char lds[131072] __attribute__((aligned(16)));
    const int tid = threadIdx.x;
    const int w = tid >> 6, l = tid & 63;
    const int wm = w >> 2, wn = w & 3;
    const int bid = blockIdx.x;
    const int swz = (bid & 7) * ((int)gridDim.x >> 3) + (bid >> 3);
    const int brow = (swz & 31) * 256;
    const int bcol = (swz >> 5) * (128 * NW);
    const int colsw = ((l & 7) ^ (l >> 3)) << 4;

    f32x4 acc[8][2 * NW] = {};
    bf16x8 areg[4][2];
    bf16x8 breg[2][NW][2];

    auto sA = [&](int t, int mh) {
#pragma unroll
        for (int i = 0; i < 2; ++i) {
            int s = (w * 2 + i) * 8 + (l >> 3);
            int r = ((s >> 6) << 7) + mh * 64 + (s & 63);
            const char* src = (const char*)Ap + (((size_t)(brow + r) * K + t * 64) << 1) + colsw;
            __builtin_amdgcn_global_load_lds(
                (const __attribute__((address_space(1))) void*)src,
                (__attribute__((address_space(3))) void*)&lds[(t & 1) * 32768 + mh * 16384 +
                                                              (w * 2 + i) * 1024],
                16, 0, 0);
        }
    };
    auto sB = [&](int t, int nh) {
#pragma unroll
        for (int i = 0; i < NW; ++i) {
            constexpr int SH = (NW == 2) ? 5 : 4;
            int s = (w * NW + i) * 8 + (l >> 3);
            int r = ((s >> SH) << (SH + 1)) + nh * (16 * NW) + (s & (16 * NW - 1));
            const char* src = (const char*)Bp + (((size_t)(bcol + r) * K + t * 64) << 1) + colsw;
            __builtin_amdgcn_global_load_lds(
                (const __attribute__((address_space(1))) void*)src,
                (__attribute__((address_space(3))) void*)&lds[65536 + (t & 1) * (NW * 16384) +
                                                              nh * (NW * 8192) + (w * NW + i) * 1024],
                16, 0, 0);
        }
    };
    auto load_a = [&](int db, int mh) {
#pragma unroll
        for (int m = 0; m < 4; ++m)
#pragma unroll
            for (int ks = 0; ks < 2; ++ks) {
                int s = wm * 64 + m * 16 + (l & 15);
                areg[m][ks] = *(const bf16x8*)(lds + db * 32768 + mh * 16384 + s * 128 +
                                               ((ks * 64 + ((l >> 4) << 4)) ^ ((l & 7) << 4)));
            }
    };
    auto load_b = [&](int db, int nh) {
#pragma unroll
        for (int n = 0; n < NW; ++n)
#pragma unroll
            for (int ks = 0; ks < 2; ++ks) {
                int s = wn * (16 * NW) + n * 16 + (l & 15);
                breg[nh][n][ks] = *(const bf16x8*)(lds + 65536 + db * (NW * 16384) +
                                                   nh * (NW * 8192) + s * 128 +
                                                   ((ks * 64 + ((l >> 4) << 4)) ^ ((l & 7) << 4)));
            }
    };
    auto mma = [&](int mh, int nh) {
#pragma unroll
        for (int m = 0; m < 4; ++m)
#pragma unroll
            for (int n = 0; n < NW; ++n)
#pragma unroll
                for (int ks = 0; ks < 2; ++ks)
                    acc[mh * 4 + m][nh * NW + n] = __builtin_amdgcn_mfma_f32_16x16x32_bf16(
                        areg[m][ks], breg[nh][n][ks], acc[mh * 4 + m][nh * NW + n], 0, 0, 0);
    };

    sA(0, 0); sB(0, 0); sB(0, 1); sA(0, 1);
    vmw<3>();
    barrier_();

    for (int t = 0; t < nt; ++t) {
        const int db = t & 1;
        const bool more = (t + 1 < nt);
        load_a(db, 0); load_b(db, 0);
        if (more) sA(t + 1, 0);
        barrier_(); lgk0_();
        __builtin_amdgcn_s_setprio(1); mma(0, 0); __builtin_amdgcn_s_setprio(0);
        __builtin_amdgcn_sched_barrier(0);
        if (more) vmw<4>(); else vmw<2>();
        barrier_();
        load_b(db, 1);
        if (more) sB(t + 1, 0);
        barrier_(); lgk0_();
        __builtin_amdgcn_s_setprio(1); mma(0, 1); __builtin_amdgcn_s_setprio(0);
        __builtin_amdgcn_sched_barrier(0);
        if (more) vmw<3>(); else vmw<0>();
        barrier_();
        load_a(db, 1);
        if (more) sB(t + 1, 1);
        barrier_(); lgk0_();
        __builtin_amdgcn_s_setprio(1); mma(1, 1); __builtin_amdgcn_s_setprio(0);
        barrier_();
        if (more) sA(t + 1, 1);
        barrier_();
        __builtin_amdgcn_s_setprio(1); mma(1, 0); __builtin_amdgcn_s_setprio(0);
        __builtin_amdgcn_sched_barrier(0);
        if (more) vmw<3>();
        barrier_();
    }

    char* wsl = lds + w * 16384;
    constexpr int E = ACT ? 2 : 4;
    constexpr int BPR = NW * 32 * E;
    constexpr int LPR = BPR / 16;
    constexpr int RPI = 64 / LPR;
#pragma unroll
    for (int m = 0; m < 8; ++m)
#pragma unroll
        for (int n = 0; n < 2 * NW; ++n)
#pragma unroll
            for (int r = 0; r < 4; ++r) {
                int row = m * 16 + ((l >> 4) << 2) + r;
                int colb = (n * 16 + (l & 15)) * E;
                float v = acc[m][n][r];
                if (ACT) {
                    *(ushort*)(wsl + row * 128 + (colb ^ ((row & 7) << 4))) = f2bf(yoso_act(v));
                } else {
                    *(float*)(wsl + row * 128 + (colb ^ ((row & 7) << 4))) = v;
                }
            }
    asm volatile("s_waitcnt lgkmcnt(0)" ::: "memory");
#pragma unroll
    for (int it = 0; it < 2 * LPR; ++it) {
        int row = it * RPI + l / LPR;
        int cb = (l % LPR) * 16;
        uint4 d = *(const uint4*)(wsl + row * 128 + (cb ^ ((row & 7) << 4)));
        int grow = brow + wm * 128 + row;
        size_t off = ((size_t)grow * N + (bcol + wn * (NW * 32))) * E + cb;
        *(uint4*)((char*)Cv + off) = d;
    }
}

// ---------------- Kernel 1: LayerNorm + l2-normalize -> Q bf16 ----------------
__global__ __launch_bounds__(256) void ln_qnorm_kernel(
    const float* __restrict__ x, const float* __restrict__ w,
    const float* __restrict__ b, ushort* __restrict__ Q) {
    __shared__ float red[2][4];
    __shared__ float red2[4];
    const int row = blockIdx.x, t = threadIdx.x;
    const int lane = t & 63, wid = t >> 6;
    const float4 v = reinterpret_cast<const float4*>(x + (size_t)row * HD)[t];
    float s  = v.x + v.y + v.z + v.w;
    float ss = v.x*v.x + v.y*v.y + v.z*v.z + v.w*v.w;
    s = wave_sum(s); ss = wave_sum(ss);
    if (lane == 0) { red[0][wid] = s; red[1][wid] = ss; }
    __syncthreads();
    float st  = red[0][0] + red[0][1] + red[0][2] + red[0][3];
    float sst = red[1][0] + red[1][1] + red[1][2] + red[1][3];
    float mu   = st * (1.0f / HD);
    float var  = sst * (1.0f / HD) - mu * mu;
    float rstd = rsqrtf(var + 1e-12f);
    const float4 wv = reinterpret_cast<const float4*>(w)[t];
    const float4 bv = reinterpret_cast<const float4*>(b)[t];
    float y0 = (v.x - mu) * rstd * wv.x + bv.x;
    float y1 = (v.y - mu) * rstd * wv.y + bv.y;
    float y2 = (v.z - mu) * rstd * wv.z + bv.z;
    float y3 = (v.w - mu) * rstd * wv.w + bv.w;
    float n2 = wave_sum(y0*y0 + y1*y1 + y2*y2 + y3*y3);
    if (lane == 0) red2[wid] = n2;
    __syncthreads();
    float nt = red2[0] + red2[1] + red2[2] + red2[3];
    float sc = 1.0f / fmaxf(sqrtf(nt), 1e-12f);
    ushort4 o;
    o.x = f2bf(y0 * sc); o.y = f2bf(y1 * sc);
    o.z = f2bf(y2 * sc); o.w = f2bf(y3 * sc);
    reinterpret_cast<ushort4*>(Q + (size_t)row * HD)[t] = o;
}

// ---------------- Kernel 2: l2-normalize k_weight rows -> Kn bf16 ----------------
__global__ __launch_bounds__(256) void knorm_kernel(
    const float* __restrict__ kw, ushort* __restrict__ Kn) {
    __shared__ float red2[4];
    const int row = blockIdx.x, t = threadIdx.x;
    const int lane = t & 63, wid = t >> 6;
    const float4 v = reinterpret_cast<const float4*>(kw + (size_t)row * HD)[t];
    float n2 = wave_sum(v.x*v.x + v.y*v.y + v.z*v.z + v.w*v.w);
    if (lane == 0) red2[wid] = n2;
    __syncthreads();
    float nt = red2[0] + red2[1] + red2[2] + red2[3];
    float sc = 1.0f / fmaxf(sqrtf(nt), 1e-12f);
    ushort4 o;
    o.x = f2bf(v.x * sc); o.y = f2bf(v.y * sc);
    o.z = f2bf(v.z * sc); o.w = f2bf(v.w * sc);
    reinterpret_cast<ushort4*>(Kn + (size_t)row * HD)[t] = o;
}

// ---------------- Kernel 3: transpose+cast q_weight [I][H] -> VT bf16 [H][I] ----------------
__global__ __launch_bounds__(256) void tcvt_kernel(
    const float* __restrict__ V, ushort* __restrict__ VT) {
    __shared__ float tile[64][65];
    const int t = threadIdx.x;
    const int bi = blockIdx.x * 64, bh = blockIdx.y * 64;
    const int r0 = t >> 4, c0 = (t & 15) << 2;
#pragma unroll
    for (int rr = 0; rr < 64; rr += 16) {
        float4 val = *reinterpret_cast<const float4*>(
            &V[(size_t)(bi + rr + r0) * HD + bh + c0]);
        tile[rr + r0][c0 + 0] = val.x; tile[rr + r0][c0 + 1] = val.y;
        tile[rr + r0][c0 + 2] = val.z; tile[rr + r0][c0 + 3] = val.w;
    }
    __syncthreads();
#pragma unroll
    for (int rr = 0; rr < 64; rr += 16) {
        ushort4 o;
        o.x = f2bf(tile[c0 + 0][rr + r0]);
        o.y = f2bf(tile[c0 + 1][rr + r0]);
        o.z = f2bf(tile[c0 + 2][rr + r0]);
        o.w = f2bf(tile[c0 + 3][rr + r0]);
        *reinterpret_cast<ushort4*>(&VT[(size_t)(bh + rr + r0) * ID + bi + c0]) = o;
    }
}

// ---------------- Kernel 6: in-place row l2-normalize + bias ----------------
__global__ __launch_bounds__(256) void outnorm_kernel(
    float* __restrict__ X, const float* __restrict__ bias) {
    __shared__ float red2[4];
    const int row = blockIdx.x, t = threadIdx.x;
    const int lane = t & 63, wid = t >> 6;
    float4 v = reinterpret_cast<float4*>(X + (size_t)row * HD)[t];
    float n2 = wave_sum(v.x*v.x + v.y*v.y + v.z*v.z + v.w*v.w);
    if (lane == 0) red2[wid] = n2;
    __syncthreads();
    float nt = red2[0] + red2[1] + red2[2] + red2[3];
    float sc = 1.0f / fmaxf(sqrtf(nt), 1e-12f);
    const float4 bv = reinterpret_cast<const float4*>(bias)[t];
    float4 o;
    o.x = v.x * sc + bv.x; o.y = v.y * sc + bv.y;
    o.z = v.z * sc + bv.z; o.w = v.w * sc + bv.w;
    reinterpret_cast<float4*>(X + (size_t)row * HD)[t] = o;
}

extern "C" void kernel_launch(void* const* d_in, const int* in_sizes, int n_in,
                              void* d_out, int out_size, void* d_ws, size_t ws_size,
                              hipStream_t stream) {
    const float* hs   = (const float*)d_in[0];  // hidden_states [4,2048,1024]
    const float* lnw  = (const float*)d_in[1];  // ln_weight [1024]
    const float* lnb  = (const float*)d_in[2];  // ln_bias [1024]
    const float* kw   = (const float*)d_in[3];  // k_weight [4096,1024]
    const float* qw   = (const float*)d_in[4];  // q_weight [4096,1024]
    const float* bias = (const float*)d_in[5];  // bias [1024]
    float* out = (float*)d_out;

    char* ws = (char*)d_ws;
    ushort* Q    = (ushort*)(ws);                                  // 16 MiB
    ushort* Kn   = (ushort*)(ws + (size_t)16777216);               //  8 MiB
    ushort* VT   = (ushort*)(ws + (size_t)16777216 + 8388608);     //  8 MiB
    ushort* Bmat = (ushort*)(ws + (size_t)16777216 + 2 * 8388608); // 64 MiB

    ln_qnorm_kernel<<<NR, 256, 0, stream>>>(hs, lnw, lnb, Q);
    knorm_kernel<<<ID, 256, 0, stream>>>(kw, Kn);
    tcvt_kernel<<<dim3(ID / 64, HD / 64), 256, 0, stream>>>(qw, VT);

    // ---- ABLATION (all scratch writes overwritten by the canonical V0 below) ----
    // V3: proven gemm8p binary on GEMM1 operands (K=1024, nt=16), half-N (2048) so
    //     the f32 output exactly fills the 64 MiB Bmat scratch. grid 512.
    gemm8p_kernel<1, 0><<<512, 512, 0, stream>>>(Q, Kn, (void*)Bmat, 2048, 1024, 16);
    // V1: no staging / no vmcnt (schedule+LDS+MFMA floor; garbage out).
    gemm1p_abl<1><<<256, 512, 0, stream>>>(Q, Kn, Bmat, ID, HD);
    // V2: no epilogue stores (acc kept live via asm sinks).
    gemm1p_abl<2><<<256, 512, 0, stream>>>(Q, Kn, Bmat, ID, HD);
    // V0: full R7 kernel — writes the CORRECT Bmat (runs last among GEMM1 variants).
    gemm1p_abl<0><<<256, 512, 0, stream>>>(Q, Kn, Bmat, ID, HD);

    // GEMM2: [8192,4096] x [1024,4096]^T -> out f32 [8192,1024]
    gemm8p_kernel<1, 0><<<(NR / 256) * (HD / 128), 512, 0, stream>>>(
        Bmat, VT, (void*)out, HD, ID, ID / 64);
    outnorm_kernel<<<NR, 256, 0, stream>>>(out, bias);
}

// Round 9
// 222.845 us; speedup vs baseline: 1.9227x; 1.9227x over previous
//
#include <hip/hip_runtime.h>

#define HD 1024
#define ID 4096
#define NR 8192

typedef float f32x4 __attribute__((ext_vector_type(4)));
typedef __bf16 bf16x8 __attribute__((ext_vector_type(8)));

__device__ inline ushort f2bf(float f) {
    union { float f; unsigned u; } v; v.f = f;
    unsigned u = v.u;
    unsigned r = (u + 0x7fffu + ((u >> 16) & 1u)) >> 16;  // RNE
    return (ushort)r;
}

__device__ inline float wave_sum(float v) {
#pragma unroll
    for (int o = 32; o > 0; o >>= 1) v += __shfl_xor(v, o, 64);
    return v;
}

template <int N> __device__ __forceinline__ void vmw() {
    static_assert(N >= 0 && N <= 4, "vmcnt");
    if constexpr (N == 0) asm volatile("s_waitcnt vmcnt(0)" ::: "memory");
    else if constexpr (N == 1) asm volatile("s_waitcnt vmcnt(1)" ::: "memory");
    else if constexpr (N == 2) asm volatile("s_waitcnt vmcnt(2)" ::: "memory");
    else if constexpr (N == 3) asm volatile("s_waitcnt vmcnt(3)" ::: "memory");
    else asm volatile("s_waitcnt vmcnt(4)" ::: "memory");
}
__device__ __forceinline__ void barrier_() {
    __builtin_amdgcn_sched_barrier(0);
    __builtin_amdgcn_s_barrier();
    __builtin_amdgcn_sched_barrier(0);
}
__device__ __forceinline__ void lgk0_() {
    asm volatile("s_waitcnt lgkmcnt(0)" ::: "memory");
    __builtin_amdgcn_sched_barrier(0);
}

// YOSO activation: t = 1 - acos(s)/pi via A&S 4.4.45 (|err| <= 6.7e-5 rad), out t^9.
__device__ __forceinline__ float yoso_act(float v) {
    float s = fminf(fmaxf(v, -0.999999f), 0.999999f);
    float a = fabsf(s);
    float p = 0.49998557f + a * (-0.06751706f + a * (0.02363794f - a * 0.00596170f));
    float q = sqrtf(1.0f - a) * p;           // acos(|s|)/pi
    float tt = (s >= 0.0f) ? 1.0f - q : q;
    float t2 = tt * tt, t4 = t2 * t2, t8 = t4 * t4;
    return t8 * tt;
}

// ======== GEMM1: 256x128 8-phase, nt=16, XCD-banded, DIRECT-store act epilogue ========
// Identical to the R4 kernel except the epilogue: act applied in-register, ushort
// stores straight to global (16-lane groups = 32-B contiguous segments; R1-proven).
// Grid MUST be 1024 = 8 xcd * 32 cu * 4 rnd.
__global__ __launch_bounds__(512, 2) void gemm1d_kernel(
    const ushort* __restrict__ Ap, const ushort* __restrict__ Bp,
    ushort* __restrict__ Cp, int N, int K, int nt) {
    __shared__ char lds[131072] __attribute__((aligned(16)));
    const int tid = threadIdx.x;
    const int w = tid >> 6, l = tid & 63;
    const int wm = w >> 2, wn = w & 3;
    const int bid = blockIdx.x;
    const int xcd = bid & 7, cu = (bid >> 3) & 31, rnd = bid >> 8;
    const int brow = (xcd * 4 + (cu >> 3)) * 256;
    const int bcol = (rnd * 8 + (cu & 7)) * 128;
    const int colsw = ((l & 7) ^ (l >> 3)) << 4;  // T2 inverse pre-swizzle on source

    f32x4 acc[8][2] = {};
    bf16x8 areg[4][2];
    bf16x8 breg[2][2];

    auto sA = [&](int t, int mh) {
#pragma unroll
        for (int i = 0; i < 2; ++i) {
            int s = (w * 2 + i) * 8 + (l >> 3);
            int r = ((s >> 6) << 7) + mh * 64 + (s & 63);
            const char* src = (const char*)Ap + (((size_t)(brow + r) * K + t * 64) << 1) + colsw;
            __builtin_amdgcn_global_load_lds(
                (const __attribute__((address_space(1))) void*)src,
                (__attribute__((address_space(3))) void*)&lds[(t & 1) * 32768 + mh * 16384 +
                                                              (w * 2 + i) * 1024],
                16, 0, 0);
        }
    };
    auto sB = [&](int t, int nh) {
        int s = w * 8 + (l >> 3);
        int r = ((s >> 4) << 5) + nh * 16 + (s & 15);
        const char* src = (const char*)Bp + (((size_t)(bcol + r) * K + t * 64) << 1) + colsw;
        __builtin_amdgcn_global_load_lds(
            (const __attribute__((address_space(1))) void*)src,
            (__attribute__((address_space(3))) void*)&lds[65536 + (t & 1) * 16384 + nh * 8192 +
                                                          w * 1024],
            16, 0, 0);
    };
    auto load_a = [&](int db, int mh) {
#pragma unroll
        for (int m = 0; m < 4; ++m)
#pragma unroll
            for (int ks = 0; ks < 2; ++ks) {
                int s = wm * 64 + m * 16 + (l & 15);
                areg[m][ks] = *(const bf16x8*)(lds + db * 32768 + mh * 16384 + s * 128 +
                                               ((ks * 64 + ((l >> 4) << 4)) ^ ((l & 7) << 4)));
            }
    };
    auto load_b = [&](int db, int nh) {
#pragma unroll
        for (int ks = 0; ks < 2; ++ks) {
            int s = wn * 16 + (l & 15);
            breg[nh][ks] = *(const bf16x8*)(lds + 65536 + db * 16384 + nh * 8192 + s * 128 +
                                            ((ks * 64 + ((l >> 4) << 4)) ^ ((l & 7) << 4)));
        }
    };
    auto mma = [&](int mh, int nh) {
#pragma unroll
        for (int m = 0; m < 4; ++m)
#pragma unroll
            for (int ks = 0; ks < 2; ++ks)
                acc[mh * 4 + m][nh] = __builtin_amdgcn_mfma_f32_16x16x32_bf16(
                    areg[m][ks], breg[nh][ks], acc[mh * 4 + m][nh], 0, 0, 0);
    };

    // prologue: u1=A.mh0, u2=B.nh0, u3=B.nh1, u4=A.mh1; land u1,u2
    sA(0, 0); sB(0, 0); sB(0, 1); sA(0, 1);
    vmw<3>();
    barrier_();

    for (int t = 0; t < nt; ++t) {
        const int db = t & 1;
        const bool more = (t + 1 < nt);
        // ph1: (mh0,nh0); stage (t+1).A.mh0
        load_a(db, 0); load_b(db, 0);
        if (more) sA(t + 1, 0);
        barrier_(); lgk0_();
        __builtin_amdgcn_s_setprio(1); mma(0, 0); __builtin_amdgcn_s_setprio(0);
        __builtin_amdgcn_sched_barrier(0);
        if (more) vmw<4>(); else vmw<2>();   // land t.B.nh1
        barrier_();
        // ph2: (mh0,nh1); stage (t+1).B.nh0
        load_b(db, 1);
        if (more) sB(t + 1, 0);
        barrier_(); lgk0_();
        __builtin_amdgcn_s_setprio(1); mma(0, 1); __builtin_amdgcn_s_setprio(0);
        __builtin_amdgcn_sched_barrier(0);
        if (more) vmw<3>(); else vmw<0>();   // land t.A.mh1
        barrier_();
        // ph3: (mh1,nh1); stage (t+1).B.nh1
        load_a(db, 1);
        if (more) sB(t + 1, 1);
        barrier_(); lgk0_();
        __builtin_amdgcn_s_setprio(1); mma(1, 1); __builtin_amdgcn_s_setprio(0);
        barrier_();
        // ph4: (mh1,nh0); stage (t+1).A.mh1
        if (more) sA(t + 1, 1);
        barrier_();
        __builtin_amdgcn_s_setprio(1); mma(1, 0); __builtin_amdgcn_s_setprio(0);
        __builtin_amdgcn_sched_barrier(0);
        if (more) vmw<3>();                  // land (t+1).u1,u2
        barrier_();
    }

    // ---- epilogue: DIRECT stores from registers (no LDS round-trip) ----
    // C frag: col = lane&15, row = (lane>>4)*4 + r. 16-lane groups -> 32-B segments.
    const int crow0 = brow + wm * 128 + ((l >> 4) << 2);
    const int ccol0 = bcol + wn * 32 + (l & 15);
#pragma unroll
    for (int m = 0; m < 8; ++m)
#pragma unroll
        for (int n = 0; n < 2; ++n)
#pragma unroll
            for (int r = 0; r < 4; ++r) {
                int row = crow0 + m * 16 + r;
                int col = ccol0 + n * 16;
                Cp[(size_t)row * N + col] = f2bf(yoso_act(acc[m][n][r]));
            }
}

// ================= GEMM2: proven 8-phase 256x128 (ACT=0, f32 out) ==========
template <int NW, int ACT>
__global__ __launch_bounds__(512, 2) void gemm8p_kernel(
    const ushort* __restrict__ Ap, const ushort* __restrict__ Bp,
    void* __restrict__ Cv, int N, int K, int nt) {
    __shared__ char lds[131072] __attribute__((aligned(16)));
    const int tid = threadIdx.x;
    const int w = tid >> 6, l = tid & 63;
    const int wm = w >> 2, wn = w & 3;
    const int bid = blockIdx.x;
    const int swz = (bid & 7) * ((int)gridDim.x >> 3) + (bid >> 3);
    const int brow = (swz & 31) * 256;
    const int bcol = (swz >> 5) * (128 * NW);
    const int colsw = ((l & 7) ^ (l >> 3)) << 4;

    f32x4 acc[8][2 * NW] = {};
    bf16x8 areg[4][2];
    bf16x8 breg[2][NW][2];

    auto sA = [&](int t, int mh) {
#pragma unroll
        for (int i = 0; i < 2; ++i) {
            int s = (w * 2 + i) * 8 + (l >> 3);
            int r = ((s >> 6) << 7) + mh * 64 + (s & 63);
            const char* src = (const char*)Ap + (((size_t)(brow + r) * K + t * 64) << 1) + colsw;
            __builtin_amdgcn_global_load_lds(
                (const __attribute__((address_space(1))) void*)src,
                (__attribute__((address_space(3))) void*)&lds[(t & 1) * 32768 + mh * 16384 +
                                                              (w * 2 + i) * 1024],
                16, 0, 0);
        }
    };
    auto sB = [&](int t, int nh) {
#pragma unroll
        for (int i = 0; i < NW; ++i) {
            constexpr int SH = (NW == 2) ? 5 : 4;
            int s = (w * NW + i) * 8 + (l >> 3);
            int r = ((s >> SH) << (SH + 1)) + nh * (16 * NW) + (s & (16 * NW - 1));
            const char* src = (const char*)Bp + (((size_t)(bcol + r) * K + t * 64) << 1) + colsw;
            __builtin_amdgcn_global_load_lds(
                (const __attribute__((address_space(1))) void*)src,
                (__attribute__((address_space(3))) void*)&lds[65536 + (t & 1) * (NW * 16384) +
                                                              nh * (NW * 8192) + (w * NW + i) * 1024],
                16, 0, 0);
        }
    };
    auto load_a = [&](int db, int mh) {
#pragma unroll
        for (int m = 0; m < 4; ++m)
#pragma unroll
            for (int ks = 0; ks < 2; ++ks) {
                int s = wm * 64 + m * 16 + (l & 15);
                areg[m][ks] = *(const bf16x8*)(lds + db * 32768 + mh * 16384 + s * 128 +
                                               ((ks * 64 + ((l >> 4) << 4)) ^ ((l & 7) << 4)));
            }
    };
    auto load_b = [&](int db, int nh) {
#pragma unroll
        for (int n = 0; n < NW; ++n)
#pragma unroll
            for (int ks = 0; ks < 2; ++ks) {
                int s = wn * (16 * NW) + n * 16 + (l & 15);
                breg[nh][n][ks] = *(const bf16x8*)(lds + 65536 + db * (NW * 16384) +
                                                   nh * (NW * 8192) + s * 128 +
                                                   ((ks * 64 + ((l >> 4) << 4)) ^ ((l & 7) << 4)));
            }
    };
    auto mma = [&](int mh, int nh) {
#pragma unroll
        for (int m = 0; m < 4; ++m)
#pragma unroll
            for (int n = 0; n < NW; ++n)
#pragma unroll
                for (int ks = 0; ks < 2; ++ks)
                    acc[mh * 4 + m][nh * NW + n] = __builtin_amdgcn_mfma_f32_16x16x32_bf16(
                        areg[m][ks], breg[nh][n][ks], acc[mh * 4 + m][nh * NW + n], 0, 0, 0);
    };

    sA(0, 0); sB(0, 0); sB(0, 1); sA(0, 1);
    vmw<3>();
    barrier_();

    for (int t = 0; t < nt; ++t) {
        const int db = t & 1;
        const bool more = (t + 1 < nt);
        load_a(db, 0); load_b(db, 0);
        if (more) sA(t + 1, 0);
        barrier_(); lgk0_();
        __builtin_amdgcn_s_setprio(1); mma(0, 0); __builtin_amdgcn_s_setprio(0);
        __builtin_amdgcn_sched_barrier(0);
        if (more) vmw<4>(); else vmw<2>();
        barrier_();
        load_b(db, 1);
        if (more) sB(t + 1, 0);
        barrier_(); lgk0_();
        __builtin_amdgcn_s_setprio(1); mma(0, 1); __builtin_amdgcn_s_setprio(0);
        __builtin_amdgcn_sched_barrier(0);
        if (more) vmw<3>(); else vmw<0>();
        barrier_();
        load_a(db, 1);
        if (more) sB(t + 1, 1);
        barrier_(); lgk0_();
        __builtin_amdgcn_s_setprio(1); mma(1, 1); __builtin_amdgcn_s_setprio(0);
        barrier_();
        if (more) sA(t + 1, 1);
        barrier_();
        __builtin_amdgcn_s_setprio(1); mma(1, 0); __builtin_amdgcn_s_setprio(0);
        __builtin_amdgcn_sched_barrier(0);
        if (more) vmw<3>();
        barrier_();
    }

    char* wsl = lds + w * 16384;
    constexpr int E = ACT ? 2 : 4;
    constexpr int BPR = NW * 32 * E;
    constexpr int LPR = BPR / 16;
    constexpr int RPI = 64 / LPR;
#pragma unroll
    for (int m = 0; m < 8; ++m)
#pragma unroll
        for (int n = 0; n < 2 * NW; ++n)
#pragma unroll
            for (int r = 0; r < 4; ++r) {
                int row = m * 16 + ((l >> 4) << 2) + r;
                int colb = (n * 16 + (l & 15)) * E;
                float v = acc[m][n][r];
                if (ACT) {
                    *(ushort*)(wsl + row * 128 + (colb ^ ((row & 7) << 4))) = f2bf(yoso_act(v));
                } else {
                    *(float*)(wsl + row * 128 + (colb ^ ((row & 7) << 4))) = v;
                }
            }
    asm volatile("s_waitcnt lgkmcnt(0)" ::: "memory");
#pragma unroll
    for (int it = 0; it < 2 * LPR; ++it) {
        int row = it * RPI + l / LPR;
        int cb = (l % LPR) * 16;
        uint4 d = *(const uint4*)(wsl + row * 128 + (cb ^ ((row & 7) << 4)));
        int grow = brow + wm * 128 + row;
        size_t off = ((size_t)grow * N + (bcol + wn * (NW * 32))) * E + cb;
        *(uint4*)((char*)Cv + off) = d;
    }
}

// ---------------- Kernel 1: LayerNorm + l2-normalize -> Q bf16 ----------------
__global__ __launch_bounds__(256) void ln_qnorm_kernel(
    const float* __restrict__ x, const float* __restrict__ w,
    const float* __restrict__ b, ushort* __restrict__ Q) {
    __shared__ float red[2][4];
    __shared__ float red2[4];
    const int row = blockIdx.x, t = threadIdx.x;
    const int lane = t & 63, wid = t >> 6;
    const float4 v = reinterpret_cast<const float4*>(x + (size_t)row * HD)[t];
    float s  = v.x + v.y + v.z + v.w;
    float ss = v.x*v.x + v.y*v.y + v.z*v.z + v.w*v.w;
    s = wave_sum(s); ss = wave_sum(ss);
    if (lane == 0) { red[0][wid] = s; red[1][wid] = ss; }
    __syncthreads();
    float st  = red[0][0] + red[0][1] + red[0][2] + red[0][3];
    float sst = red[1][0] + red[1][1] + red[1][2] + red[1][3];
    float mu   = st * (1.0f / HD);
    float var  = sst * (1.0f / HD) - mu * mu;
    float rstd = rsqrtf(var + 1e-12f);
    const float4 wv = reinterpret_cast<const float4*>(w)[t];
    const float4 bv = reinterpret_cast<const float4*>(b)[t];
    float y0 = (v.x - mu) * rstd * wv.x + bv.x;
    float y1 = (v.y - mu) * rstd * wv.y + bv.y;
    float y2 = (v.z - mu) * rstd * wv.z + bv.z;
    float y3 = (v.w - mu) * rstd * wv.w + bv.w;
    float n2 = wave_sum(y0*y0 + y1*y1 + y2*y2 + y3*y3);
    if (lane == 0) red2[wid] = n2;
    __syncthreads();
    float nt = red2[0] + red2[1] + red2[2] + red2[3];
    float sc = 1.0f / fmaxf(sqrtf(nt), 1e-12f);
    ushort4 o;
    o.x = f2bf(y0 * sc); o.y = f2bf(y1 * sc);
    o.z = f2bf(y2 * sc); o.w = f2bf(y3 * sc);
    reinterpret_cast<ushort4*>(Q + (size_t)row * HD)[t] = o;
}

// ---------------- Kernel 2: l2-normalize k_weight rows -> Kn bf16 ----------------
__global__ __launch_bounds__(256) void knorm_kernel(
    const float* __restrict__ kw, ushort* __restrict__ Kn) {
    __shared__ float red2[4];
    const int row = blockIdx.x, t = threadIdx.x;
    const int lane = t & 63, wid = t >> 6;
    const float4 v = reinterpret_cast<const float4*>(kw + (size_t)row * HD)[t];
    float n2 = wave_sum(v.x*v.x + v.y*v.y + v.z*v.z + v.w*v.w);
    if (lane == 0) red2[wid] = n2;
    __syncthreads();
    float nt = red2[0] + red2[1] + red2[2] + red2[3];
    float sc = 1.0f / fmaxf(sqrtf(nt), 1e-12f);
    ushort4 o;
    o.x = f2bf(v.x * sc); o.y = f2bf(v.y * sc);
    o.z = f2bf(v.z * sc); o.w = f2bf(v.w * sc);
    reinterpret_cast<ushort4*>(Kn + (size_t)row * HD)[t] = o;
}

// ---------------- Kernel 3: transpose+cast q_weight [I][H] -> VT bf16 [H][I] ----------------
__global__ __launch_bounds__(256) void tcvt_kernel(
    const float* __restrict__ V, ushort* __restrict__ VT) {
    __shared__ float tile[64][65];
    const int t = threadIdx.x;
    const int bi = blockIdx.x * 64, bh = blockIdx.y * 64;
    const int r0 = t >> 4, c0 = (t & 15) << 2;
#pragma unroll
    for (int rr = 0; rr < 64; rr += 16) {
        float4 val = *reinterpret_cast<const float4*>(
            &V[(size_t)(bi + rr + r0) * HD + bh + c0]);
        tile[rr + r0][c0 + 0] = val.x; tile[rr + r0][c0 + 1] = val.y;
        tile[rr + r0][c0 + 2] = val.z; tile[rr + r0][c0 + 3] = val.w;
    }
    __syncthreads();
#pragma unroll
    for (int rr = 0; rr < 64; rr += 16) {
        ushort4 o;
        o.x = f2bf(tile[c0 + 0][rr + r0]);
        o.y = f2bf(tile[c0 + 1][rr + r0]);
        o.z = f2bf(tile[c0 + 2][rr + r0]);
        o.w = f2bf(tile[c0 + 3][rr + r0]);
        *reinterpret_cast<ushort4*>(&VT[(size_t)(bh + rr + r0) * ID + bi + c0]) = o;
    }
}

// ---------------- Kernel 6: in-place row l2-normalize + bias ----------------
__global__ __launch_bounds__(256) void outnorm_kernel(
    float* __restrict__ X, const float* __restrict__ bias) {
    __shared__ float red2[4];
    const int row = blockIdx.x, t = threadIdx.x;
    const int lane = t & 63, wid = t >> 6;
    float4 v = reinterpret_cast<float4*>(X + (size_t)row * HD)[t];
    float n2 = wave_sum(v.x*v.x + v.y*v.y + v.z*v.z + v.w*v.w);
    if (lane == 0) red2[wid] = n2;
    __syncthreads();
    float nt = red2[0] + red2[1] + red2[2] + red2[3];
    float sc = 1.0f / fmaxf(sqrtf(nt), 1e-12f);
    const float4 bv = reinterpret_cast<const float4*>(bias)[t];
    float4 o;
    o.x = v.x * sc + bv.x; o.y = v.y * sc + bv.y;
    o.z = v.z * sc + bv.z; o.w = v.w * sc + bv.w;
    reinterpret_cast<float4*>(X + (size_t)row * HD)[t] = o;
}

extern "C" void kernel_launch(void* const* d_in, const int* in_sizes, int n_in,
                              void* d_out, int out_size, void* d_ws, size_t ws_size,
                              hipStream_t stream) {
    const float* hs   = (const float*)d_in[0];  // hidden_states [4,2048,1024]
    const float* lnw  = (const float*)d_in[1];  // ln_weight [1024]
    const float* lnb  = (const float*)d_in[2];  // ln_bias [1024]
    const float* kw   = (const float*)d_in[3];  // k_weight [4096,1024]
    const float* qw   = (const float*)d_in[4];  // q_weight [4096,1024]
    const float* bias = (const float*)d_in[5];  // bias [1024]
    float* out = (float*)d_out;

    char* ws = (char*)d_ws;
    ushort* Q    = (ushort*)(ws);                                  // 16 MiB
    ushort* Kn   = (ushort*)(ws + (size_t)16777216);               //  8 MiB
    ushort* VT   = (ushort*)(ws + (size_t)16777216 + 8388608);     //  8 MiB
    ushort* Bmat = (ushort*)(ws + (size_t)16777216 + 2 * 8388608); // 64 MiB

    ln_qnorm_kernel<<<NR, 256, 0, stream>>>(hs, lnw, lnb, Q);
    knorm_kernel<<<ID, 256, 0, stream>>>(kw, Kn);
    tcvt_kernel<<<dim3(ID / 64, HD / 64), 256, 0, stream>>>(qw, VT);
    // GEMM1: [8192,1024] x [4096,1024]^T -> act -> Bmat bf16 [8192,4096]
    //        8-phase 256x128, nt=16, banded map, DIRECT-store epilogue; grid 1024
    gemm1d_kernel<<<(NR / 256) * (ID / 128), 512, 0, stream>>>(
        Q, Kn, Bmat, ID, HD, HD / 64);
    // GEMM2: [8192,4096] x [1024,4096]^T -> out f32 [8192,1024]
    gemm8p_kernel<1, 0><<<(NR / 256) * (HD / 128), 512, 0, stream>>>(
        Bmat, VT, (void*)out, HD, ID, ID / 64);
    outnorm_kernel<<<NR, 256, 0, stream>>>(out, bias);
}

// Round 10
// 202.462 us; speedup vs baseline: 2.1163x; 1.1007x over previous
//
#include <hip/hip_runtime.h>

#define HD 1024
#define ID 4096
#define NR 8192

typedef float f32x4 __attribute__((ext_vector_type(4)));
typedef __bf16 bf16x8 __attribute__((ext_vector_type(8)));

__device__ inline ushort f2bf(float f) {
    union { float f; unsigned u; } v; v.f = f;
    unsigned u = v.u;
    unsigned r = (u + 0x7fffu + ((u >> 16) & 1u)) >> 16;  // RNE
    return (ushort)r;
}

__device__ inline float wave_sum(float v) {
#pragma unroll
    for (int o = 32; o > 0; o >>= 1) v += __shfl_xor(v, o, 64);
    return v;
}

template <int N> __device__ __forceinline__ void vmw() {
    static_assert(N >= 0 && N <= 4, "vmcnt");
    if constexpr (N == 0) asm volatile("s_waitcnt vmcnt(0)" ::: "memory");
    else if constexpr (N == 1) asm volatile("s_waitcnt vmcnt(1)" ::: "memory");
    else if constexpr (N == 2) asm volatile("s_waitcnt vmcnt(2)" ::: "memory");
    else if constexpr (N == 3) asm volatile("s_waitcnt vmcnt(3)" ::: "memory");
    else asm volatile("s_waitcnt vmcnt(4)" ::: "memory");
}
__device__ __forceinline__ void barrier_() {
    __builtin_amdgcn_sched_barrier(0);
    __builtin_amdgcn_s_barrier();
    __builtin_amdgcn_sched_barrier(0);
}
__device__ __forceinline__ void lgk0_() {
    asm volatile("s_waitcnt lgkmcnt(0)" ::: "memory");
    __builtin_amdgcn_sched_barrier(0);
}

// YOSO activation: t = 1 - acos(s)/pi via A&S 4.4.45 (|err| <= 6.7e-5 rad), out t^9.
__device__ __forceinline__ float yoso_act(float v) {
    float s = fminf(fmaxf(v, -0.999999f), 0.999999f);
    float a = fabsf(s);
    float p = 0.49998557f + a * (-0.06751706f + a * (0.02363794f - a * 0.00596170f));
    float q = sqrtf(1.0f - a) * p;           // acos(|s|)/pi
    float tt = (s >= 0.0f) ? 1.0f - q : q;
    float t2 = tt * tt, t4 = t2 * t2, t8 = t4 * t4;
    return t8 * tt;
}

// ======== GEMM1: m97-style 2-barrier 128x128, BK=64, 4 waves, 32 KiB LDS (4 blk/CU) ========
// R1's proven kernel + T2 XOR-swizzle (conflict-free ds_read_b128) + XCD-banded map +
// in-register poly-act direct-store epilogue. Grid MUST be 2048 = 8 xcd * 32 cu * 8 rnd.
// Swizzle (rule 21): LDS dest linear; source col pre-swizzled ((l&7)^(l>>3))<<4;
// fragment reads XOR ((row&7)<<4).
__global__ __launch_bounds__(256, 4) void gemm1s_kernel(
    const ushort* __restrict__ Ap, const ushort* __restrict__ Bp,
    ushort* __restrict__ Cp, int N, int K) {
    __shared__ ushort la[128 * 64] __attribute__((aligned(16)));
    __shared__ ushort lb[128 * 64] __attribute__((aligned(16)));
    const int tid = threadIdx.x;
    const int w = tid >> 6, lane = tid & 63;
    const int bid = blockIdx.x;
    const int xcd = bid & 7, cu = (bid >> 3) & 31, rnd = bid >> 8;
    const int brow = (xcd * 8 + (cu >> 2)) * 128;   // per-XCD A footprint 2 MiB
    const int bcol = (rnd * 4 + (cu & 3)) * 128;    // per-XCD B footprint 1 MiB
    const int wr = (w >> 1) * 64;
    const int wc = (w & 1) * 64;
    f32x4 acc[4][4] = {};
    const int srow = lane >> 3;                       // row within 8-row stripe
    const int scolb = ((lane & 7) ^ (lane >> 3)) << 4;  // pre-swizzled source col (bytes)

    for (int k0 = 0; k0 < K; k0 += 64) {
#pragma unroll
        for (int it = 0; it < 4; ++it) {
            const int rb = w * 32 + it * 8;
            const char* ga = (const char*)(Ap + (size_t)(brow + rb + srow) * K + k0) + scolb;
            const char* gb = (const char*)(Bp + (size_t)(bcol + rb + srow) * K + k0) + scolb;
            __builtin_amdgcn_global_load_lds(
                (const __attribute__((address_space(1))) void*)ga,
                (__attribute__((address_space(3))) void*)&la[rb * 64], 16, 0, 0);
            __builtin_amdgcn_global_load_lds(
                (const __attribute__((address_space(1))) void*)gb,
                (__attribute__((address_space(3))) void*)&lb[rb * 64], 16, 0, 0);
        }
        __syncthreads();
#pragma unroll
        for (int ks = 0; ks < 2; ++ks) {
            bf16x8 af[4], bfr[4];
            const int colb = ks * 64 + ((lane >> 4) << 4);  // byte offset within 128-B row
            const int xk = (lane & 7) << 4;                 // row&7 == lane&7 for all frags
#pragma unroll
            for (int m = 0; m < 4; ++m)
                af[m] = *(const bf16x8*)((const char*)la +
                                         (wr + m * 16 + (lane & 15)) * 128 + (colb ^ xk));
#pragma unroll
            for (int n = 0; n < 4; ++n)
                bfr[n] = *(const bf16x8*)((const char*)lb +
                                          (wc + n * 16 + (lane & 15)) * 128 + (colb ^ xk));
#pragma unroll
            for (int m = 0; m < 4; ++m)
#pragma unroll
                for (int n = 0; n < 4; ++n)
                    acc[m][n] = __builtin_amdgcn_mfma_f32_16x16x32_bf16(
                        af[m], bfr[n], acc[m][n], 0, 0, 0);
        }
        __syncthreads();
    }
    // epilogue: in-register act, direct ushort stores (16-lane groups = 32-B segments)
    const int crow0 = brow + wr + ((lane >> 4) << 2);
    const int ccol0 = bcol + wc + (lane & 15);
#pragma unroll
    for (int m = 0; m < 4; ++m)
#pragma unroll
        for (int n = 0; n < 4; ++n)
#pragma unroll
            for (int r = 0; r < 4; ++r) {
                int row = crow0 + m * 16 + r;
                int col = ccol0 + n * 16;
                Cp[(size_t)row * N + col] = f2bf(yoso_act(acc[m][n][r]));
            }
}

// ================= GEMM2: proven 8-phase 256x128 (ACT=0, f32 out) ==========
template <int NW, int ACT>
__global__ __launch_bounds__(512, 2) void gemm8p_kernel(
    const ushort* __restrict__ Ap, const ushort* __restrict__ Bp,
    void* __restrict__ Cv, int N, int K, int nt) {
    __shared__ char lds[131072] __attribute__((aligned(16)));
    const int tid = threadIdx.x;
    const int w = tid >> 6, l = tid & 63;
    const int wm = w >> 2, wn = w & 3;
    const int bid = blockIdx.x;
    const int swz = (bid & 7) * ((int)gridDim.x >> 3) + (bid >> 3);
    const int brow = (swz & 31) * 256;
    const int bcol = (swz >> 5) * (128 * NW);
    const int colsw = ((l & 7) ^ (l >> 3)) << 4;

    f32x4 acc[8][2 * NW] = {};
    bf16x8 areg[4][2];
    bf16x8 breg[2][NW][2];

    auto sA = [&](int t, int mh) {
#pragma unroll
        for (int i = 0; i < 2; ++i) {
            int s = (w * 2 + i) * 8 + (l >> 3);
            int r = ((s >> 6) << 7) + mh * 64 + (s & 63);
            const char* src = (const char*)Ap + (((size_t)(brow + r) * K + t * 64) << 1) + colsw;
            __builtin_amdgcn_global_load_lds(
                (const __attribute__((address_space(1))) void*)src,
                (__attribute__((address_space(3))) void*)&lds[(t & 1) * 32768 + mh * 16384 +
                                                              (w * 2 + i) * 1024],
                16, 0, 0);
        }
    };
    auto sB = [&](int t, int nh) {
#pragma unroll
        for (int i = 0; i < NW; ++i) {
            constexpr int SH = (NW == 2) ? 5 : 4;
            int s = (w * NW + i) * 8 + (l >> 3);
            int r = ((s >> SH) << (SH + 1)) + nh * (16 * NW) + (s & (16 * NW - 1));
            const char* src = (const char*)Bp + (((size_t)(bcol + r) * K + t * 64) << 1) + colsw;
            __builtin_amdgcn_global_load_lds(
                (const __attribute__((address_space(1))) void*)src,
                (__attribute__((address_space(3))) void*)&lds[65536 + (t & 1) * (NW * 16384) +
                                                              nh * (NW * 8192) + (w * NW + i) * 1024],
                16, 0, 0);
        }
    };
    auto load_a = [&](int db, int mh) {
#pragma unroll
        for (int m = 0; m < 4; ++m)
#pragma unroll
            for (int ks = 0; ks < 2; ++ks) {
                int s = wm * 64 + m * 16 + (l & 15);
                areg[m][ks] = *(const bf16x8*)(lds + db * 32768 + mh * 16384 + s * 128 +
                                               ((ks * 64 + ((l >> 4) << 4)) ^ ((l & 7) << 4)));
            }
    };
    auto load_b = [&](int db, int nh) {
#pragma unroll
        for (int n = 0; n < NW; ++n)
#pragma unroll
            for (int ks = 0; ks < 2; ++ks) {
                int s = wn * (16 * NW) + n * 16 + (l & 15);
                breg[nh][n][ks] = *(const bf16x8*)(lds + 65536 + db * (NW * 16384) +
                                                   nh * (NW * 8192) + s * 128 +
                                                   ((ks * 64 + ((l >> 4) << 4)) ^ ((l & 7) << 4)));
            }
    };
    auto mma = [&](int mh, int nh) {
#pragma unroll
        for (int m = 0; m < 4; ++m)
#pragma unroll
            for (int n = 0; n < NW; ++n)
#pragma unroll
                for (int ks = 0; ks < 2; ++ks)
                    acc[mh * 4 + m][nh * NW + n] = __builtin_amdgcn_mfma_f32_16x16x32_bf16(
                        areg[m][ks], breg[nh][n][ks], acc[mh * 4 + m][nh * NW + n], 0, 0, 0);
    };

    sA(0, 0); sB(0, 0); sB(0, 1); sA(0, 1);
    vmw<3>();
    barrier_();

    for (int t = 0; t < nt; ++t) {
        const int db = t & 1;
        const bool more = (t + 1 < nt);
        load_a(db, 0); load_b(db, 0);
        if (more) sA(t + 1, 0);
        barrier_(); lgk0_();
        __builtin_amdgcn_s_setprio(1); mma(0, 0); __builtin_amdgcn_s_setprio(0);
        __builtin_amdgcn_sched_barrier(0);
        if (more) vmw<4>(); else vmw<2>();
        barrier_();
        load_b(db, 1);
        if (more) sB(t + 1, 0);
        barrier_(); lgk0_();
        __builtin_amdgcn_s_setprio(1); mma(0, 1); __builtin_amdgcn_s_setprio(0);
        __builtin_amdgcn_sched_barrier(0);
        if (more) vmw<3>(); else vmw<0>();
        barrier_();
        load_a(db, 1);
        if (more) sB(t + 1, 1);
        barrier_(); lgk0_();
        __builtin_amdgcn_s_setprio(1); mma(1, 1); __builtin_amdgcn_s_setprio(0);
        barrier_();
        if (more) sA(t + 1, 1);
        barrier_();
        __builtin_amdgcn_s_setprio(1); mma(1, 0); __builtin_amdgcn_s_setprio(0);
        __builtin_amdgcn_sched_barrier(0);
        if (more) vmw<3>();
        barrier_();
    }

    char* wsl = lds + w * 16384;
    constexpr int E = ACT ? 2 : 4;
    constexpr int BPR = NW * 32 * E;
    constexpr int LPR = BPR / 16;
    constexpr int RPI = 64 / LPR;
#pragma unroll
    for (int m = 0; m < 8; ++m)
#pragma unroll
        for (int n = 0; n < 2 * NW; ++n)
#pragma unroll
            for (int r = 0; r < 4; ++r) {
                int row = m * 16 + ((l >> 4) << 2) + r;
                int colb = (n * 16 + (l & 15)) * E;
                float v = acc[m][n][r];
                if (ACT) {
                    *(ushort*)(wsl + row * 128 + (colb ^ ((row & 7) << 4))) = f2bf(yoso_act(v));
                } else {
                    *(float*)(wsl + row * 128 + (colb ^ ((row & 7) << 4))) = v;
                }
            }
    asm volatile("s_waitcnt lgkmcnt(0)" ::: "memory");
#pragma unroll
    for (int it = 0; it < 2 * LPR; ++it) {
        int row = it * RPI + l / LPR;
        int cb = (l % LPR) * 16;
        uint4 d = *(const uint4*)(wsl + row * 128 + (cb ^ ((row & 7) << 4)));
        int grow = brow + wm * 128 + row;
        size_t off = ((size_t)grow * N + (bcol + wn * (NW * 32))) * E + cb;
        *(uint4*)((char*)Cv + off) = d;
    }
}

// ---------------- Kernel 1: LayerNorm + l2-normalize -> Q bf16 ----------------
__global__ __launch_bounds__(256) void ln_qnorm_kernel(
    const float* __restrict__ x, const float* __restrict__ w,
    const float* __restrict__ b, ushort* __restrict__ Q) {
    __shared__ float red[2][4];
    __shared__ float red2[4];
    const int row = blockIdx.x, t = threadIdx.x;
    const int lane = t & 63, wid = t >> 6;
    const float4 v = reinterpret_cast<const float4*>(x + (size_t)row * HD)[t];
    float s  = v.x + v.y + v.z + v.w;
    float ss = v.x*v.x + v.y*v.y + v.z*v.z + v.w*v.w;
    s = wave_sum(s); ss = wave_sum(ss);
    if (lane == 0) { red[0][wid] = s; red[1][wid] = ss; }
    __syncthreads();
    float st  = red[0][0] + red[0][1] + red[0][2] + red[0][3];
    float sst = red[1][0] + red[1][1] + red[1][2] + red[1][3];
    float mu   = st * (1.0f / HD);
    float var  = sst * (1.0f / HD) - mu * mu;
    float rstd = rsqrtf(var + 1e-12f);
    const float4 wv = reinterpret_cast<const float4*>(w)[t];
    const float4 bv = reinterpret_cast<const float4*>(b)[t];
    float y0 = (v.x - mu) * rstd * wv.x + bv.x;
    float y1 = (v.y - mu) * rstd * wv.y + bv.y;
    float y2 = (v.z - mu) * rstd * wv.z + bv.z;
    float y3 = (v.w - mu) * rstd * wv.w + bv.w;
    float n2 = wave_sum(y0*y0 + y1*y1 + y2*y2 + y3*y3);
    if (lane == 0) red2[wid] = n2;
    __syncthreads();
    float nt = red2[0] + red2[1] + red2[2] + red2[3];
    float sc = 1.0f / fmaxf(sqrtf(nt), 1e-12f);
    ushort4 o;
    o.x = f2bf(y0 * sc); o.y = f2bf(y1 * sc);
    o.z = f2bf(y2 * sc); o.w = f2bf(y3 * sc);
    reinterpret_cast<ushort4*>(Q + (size_t)row * HD)[t] = o;
}

// ---------------- Kernel 2: l2-normalize k_weight rows -> Kn bf16 ----------------
__global__ __launch_bounds__(256) void knorm_kernel(
    const float* __restrict__ kw, ushort* __restrict__ Kn) {
    __shared__ float red2[4];
    const int row = blockIdx.x, t = threadIdx.x;
    const int lane = t & 63, wid = t >> 6;
    const float4 v = reinterpret_cast<const float4*>(kw + (size_t)row * HD)[t];
    float n2 = wave_sum(v.x*v.x + v.y*v.y + v.z*v.z + v.w*v.w);
    if (lane == 0) red2[wid] = n2;
    __syncthreads();
    float nt = red2[0] + red2[1] + red2[2] + red2[3];
    float sc = 1.0f / fmaxf(sqrtf(nt), 1e-12f);
    ushort4 o;
    o.x = f2bf(v.x * sc); o.y = f2bf(v.y * sc);
    o.z = f2bf(v.z * sc); o.w = f2bf(v.w * sc);
    reinterpret_cast<ushort4*>(Kn + (size_t)row * HD)[t] = o;
}

// ---------------- Kernel 3: transpose+cast q_weight [I][H] -> VT bf16 [H][I] ----------------
__global__ __launch_bounds__(256) void tcvt_kernel(
    const float* __restrict__ V, ushort* __restrict__ VT) {
    __shared__ float tile[64][65];
    const int t = threadIdx.x;
    const int bi = blockIdx.x * 64, bh = blockIdx.y * 64;
    const int r0 = t >> 4, c0 = (t & 15) << 2;
#pragma unroll
    for (int rr = 0; rr < 64; rr += 16) {
        float4 val = *reinterpret_cast<const float4*>(
            &V[(size_t)(bi + rr + r0) * HD + bh + c0]);
        tile[rr + r0][c0 + 0] = val.x; tile[rr + r0][c0 + 1] = val.y;
        tile[rr + r0][c0 + 2] = val.z; tile[rr + r0][c0 + 3] = val.w;
    }
    __syncthreads();
#pragma unroll
    for (int rr = 0; rr < 64; rr += 16) {
        ushort4 o;
        o.x = f2bf(tile[c0 + 0][rr + r0]);
        o.y = f2bf(tile[c0 + 1][rr + r0]);
        o.z = f2bf(tile[c0 + 2][rr + r0]);
        o.w = f2bf(tile[c0 + 3][rr + r0]);
        *reinterpret_cast<ushort4*>(&VT[(size_t)(bh + rr + r0) * ID + bi + c0]) = o;
    }
}

// ---------------- Kernel 6: in-place row l2-normalize + bias ----------------
__global__ __launch_bounds__(256) void outnorm_kernel(
    float* __restrict__ X, const float* __restrict__ bias) {
    __shared__ float red2[4];
    const int row = blockIdx.x, t = threadIdx.x;
    const int lane = t & 63, wid = t >> 6;
    float4 v = reinterpret_cast<float4*>(X + (size_t)row * HD)[t];
    float n2 = wave_sum(v.x*v.x + v.y*v.y + v.z*v.z + v.w*v.w);
    if (lane == 0) red2[wid] = n2;
    __syncthreads();
    float nt = red2[0] + red2[1] + red2[2] + red2[3];
    float sc = 1.0f / fmaxf(sqrtf(nt), 1e-12f);
    const float4 bv = reinterpret_cast<const float4*>(bias)[t];
    float4 o;
    o.x = v.x * sc + bv.x; o.y = v.y * sc + bv.y;
    o.z = v.z * sc + bv.z; o.w = v.w * sc + bv.w;
    reinterpret_cast<float4*>(X + (size_t)row * HD)[t] = o;
}

extern "C" void kernel_launch(void* const* d_in, const int* in_sizes, int n_in,
                              void* d_out, int out_size, void* d_ws, size_t ws_size,
                              hipStream_t stream) {
    const float* hs   = (const float*)d_in[0];  // hidden_states [4,2048,1024]
    const float* lnw  = (const float*)d_in[1];  // ln_weight [1024]
    const float* lnb  = (const float*)d_in[2];  // ln_bias [1024]
    const float* kw   = (const float*)d_in[3];  // k_weight [4096,1024]
    const float* qw   = (const float*)d_in[4];  // q_weight [4096,1024]
    const float* bias = (const float*)d_in[5];  // bias [1024]
    float* out = (float*)d_out;

    char* ws = (char*)d_ws;
    ushort* Q    = (ushort*)(ws);                                  // 16 MiB
    ushort* Kn   = (ushort*)(ws + (size_t)16777216);               //  8 MiB
    ushort* VT   = (ushort*)(ws + (size_t)16777216 + 8388608);     //  8 MiB
    ushort* Bmat = (ushort*)(ws + (size_t)16777216 + 2 * 8388608); // 64 MiB

    ln_qnorm_kernel<<<NR, 256, 0, stream>>>(hs, lnw, lnb, Q);
    knorm_kernel<<<ID, 256, 0, stream>>>(kw, Kn);
    tcvt_kernel<<<dim3(ID / 64, HD / 64), 256, 0, stream>>>(qw, VT);
    // GEMM1: [8192,1024] x [4096,1024]^T -> act -> Bmat bf16 [8192,4096]
    //        m97-style 2-barrier 128x128, 4 blk/CU, swizzled; grid 2048 = 8*32*8
    gemm1s_kernel<<<(NR / 128) * (ID / 128), 256, 0, stream>>>(
        Q, Kn, Bmat, ID, HD);
    // GEMM2: [8192,4096] x [1024,4096]^T -> out f32 [8192,1024]
    gemm8p_kernel<1, 0><<<(NR / 256) * (HD / 128), 512, 0, stream>>>(
        Bmat, VT, (void*)out, HD, ID, ID / 64);
    outnorm_kernel<<<NR, 256, 0, stream>>>(out, bias);
}